// Round 1
// baseline (365.726 us; speedup 1.0000x reference)
//
#include <hip/hip_runtime.h>

#define T_STEPS 512
#define BATCH 64

// fp32 casts of np.exp(-1/20), np.exp(-1/5)
__device__ constexpr float ALPHA_ = 0.95122942450071400910f;
__device__ constexpr float BETA_  = 0.81873075307798185867f;

// ---------------------------------------------------------------------------
// GEMM: C[M,N] = A[M,K] @ B[K,N] + bias[N]
// BM=BN=64, BK=16, 256 threads, 4x4 per thread, padded LDS.
// M,N,K all multiples of tile dims for every call here (no bounds checks).
// ---------------------------------------------------------------------------
__global__ __launch_bounds__(256) void gemm_bias(
    const float* __restrict__ A, const float* __restrict__ B,
    const float* __restrict__ bias, float* __restrict__ C,
    int M, int N, int K) {
  __shared__ float As[16][64 + 4];
  __shared__ float Bs[16][64 + 4];
  const int tid = threadIdx.x;
  const int tx = tid & 15;        // 0..15 -> N dim
  const int ty = tid >> 4;        // 0..15 -> M dim
  const int row0 = blockIdx.y * 64;
  const int col0 = blockIdx.x * 64;

  float acc[4][4] = {};

  // A tile load: 64x16 floats, float4 along K
  const int a_m = tid >> 2;            // 0..63
  const int a_k = (tid & 3) * 4;       // 0,4,8,12
  // B tile load: 16x64 floats, float4 along N
  const int b_k = tid >> 4;            // 0..15
  const int b_n = (tid & 15) * 4;      // 0..60

  const float* Aptr = A + (size_t)(row0 + a_m) * K + a_k;
  const float* Bptr = B + (size_t)b_k * N + col0 + b_n;

  for (int k0 = 0; k0 < K; k0 += 16) {
    const float4 av = *(const float4*)(Aptr + k0);
    const float4 bv = *(const float4*)(Bptr + (size_t)k0 * N);
    __syncthreads();
    As[a_k + 0][a_m] = av.x;
    As[a_k + 1][a_m] = av.y;
    As[a_k + 2][a_m] = av.z;
    As[a_k + 3][a_m] = av.w;
    *(float4*)&Bs[b_k][b_n] = bv;
    __syncthreads();
#pragma unroll
    for (int k = 0; k < 16; ++k) {
      const float4 ra = *(const float4*)&As[k][ty * 4];
      const float4 rb = *(const float4*)&Bs[k][tx * 4];
      acc[0][0] += ra.x * rb.x; acc[0][1] += ra.x * rb.y; acc[0][2] += ra.x * rb.z; acc[0][3] += ra.x * rb.w;
      acc[1][0] += ra.y * rb.x; acc[1][1] += ra.y * rb.y; acc[1][2] += ra.y * rb.z; acc[1][3] += ra.y * rb.w;
      acc[2][0] += ra.z * rb.x; acc[2][1] += ra.z * rb.y; acc[2][2] += ra.z * rb.z; acc[2][3] += ra.z * rb.w;
      acc[3][0] += ra.w * rb.x; acc[3][1] += ra.w * rb.y; acc[3][2] += ra.w * rb.z; acc[3][3] += ra.w * rb.w;
    }
  }

#pragma unroll
  for (int m = 0; m < 4; ++m) {
    const int r = row0 + ty * 4 + m;
#pragma unroll
    for (int n = 0; n < 4; ++n) {
      const int c = col0 + tx * 4 + n;
      C[(size_t)r * N + c] = acc[m][n] + bias[c];
    }
  }
}

// ---------------------------------------------------------------------------
// LIF scan over T (sequential), in-place: xt[b,t,h] -> spikes[b,t,h].
// One thread per (b,h). 4x unrolled so loads pipeline ahead of the chain.
// ---------------------------------------------------------------------------
template <int H, bool ACCUM>
__global__ void lif_scan(float* __restrict__ xt, float* __restrict__ tsum) {
  const int n = blockIdx.x * blockDim.x + threadIdx.x;  // < BATCH*H
  const int b = n / H;
  const int h = n % H;
  float* p = xt + (size_t)b * T_STEPS * H + h;

  float v = 0.f, cur = 0.f, ts = 0.f;
  for (int t = 0; t < T_STEPS; t += 4) {
    const float x0 = p[0 * H];
    const float x1 = p[1 * H];
    const float x2 = p[2 * H];
    const float x3 = p[3 * H];

    cur = BETA_ * cur + x0; v = ALPHA_ * v + cur;
    { const float s = (v >= 1.f) ? 1.f : 0.f; p[0 * H] = s; ts += s; v = (v >= 1.f) ? 0.f : v; }
    cur = BETA_ * cur + x1; v = ALPHA_ * v + cur;
    { const float s = (v >= 1.f) ? 1.f : 0.f; p[1 * H] = s; ts += s; v = (v >= 1.f) ? 0.f : v; }
    cur = BETA_ * cur + x2; v = ALPHA_ * v + cur;
    { const float s = (v >= 1.f) ? 1.f : 0.f; p[2 * H] = s; ts += s; v = (v >= 1.f) ? 0.f : v; }
    cur = BETA_ * cur + x3; v = ALPHA_ * v + cur;
    { const float s = (v >= 1.f) ? 1.f : 0.f; p[3 * H] = s; ts += s; v = (v >= 1.f) ? 0.f : v; }

    p += 4 * H;
  }
  if constexpr (ACCUM) tsum[n] = ts;
}

// ---------------------------------------------------------------------------
// LayerNorm in-place over last dim H. One wave (64 lanes) per row.
// ---------------------------------------------------------------------------
template <int H>
__global__ __launch_bounds__(256) void layernorm_inplace(
    float* __restrict__ x, const float* __restrict__ scale,
    const float* __restrict__ bias) {
  const int wave = threadIdx.x >> 6;
  const int lane = threadIdx.x & 63;
  const int row = blockIdx.x * 4 + wave;
  float* p = x + (size_t)row * H;
  constexpr int PER = H / 64;

  float vals[PER];
#pragma unroll
  for (int j = 0; j < PER; ++j) vals[j] = p[lane + j * 64];

  float s = 0.f;
#pragma unroll
  for (int j = 0; j < PER; ++j) s += vals[j];
#pragma unroll
  for (int off = 32; off > 0; off >>= 1) s += __shfl_xor(s, off);
  const float m = s / (float)H;

  float vs = 0.f;
#pragma unroll
  for (int j = 0; j < PER; ++j) { const float d = vals[j] - m; vs += d * d; }
#pragma unroll
  for (int off = 32; off > 0; off >>= 1) vs += __shfl_xor(vs, off);
  const float var = vs / (float)H;
  const float inv = 1.0f / sqrtf(var + 1e-6f);

#pragma unroll
  for (int j = 0; j < PER; ++j) {
    const int c = lane + j * 64;
    p[c] = (vals[j] - m) * inv * scale[c] + bias[c];
  }
}

// ---------------------------------------------------------------------------
// Finalize: tsum[4096] (per-(b,h) spike counts of layer 3) ->
//   out[0:2]  logits = pooled @ Wc + bc
//   out[2:66] pooled[b] = mean over (t,h)
//   out[66]   mean over everything
// ---------------------------------------------------------------------------
__global__ void finalize(const float* __restrict__ tsum,
                         const float* __restrict__ Wc,
                         const float* __restrict__ bc,
                         float* __restrict__ out) {
  const int b = threadIdx.x;  // 64 threads, one wave
  float s = 0.f;
  for (int h = 0; h < 64; ++h) s += tsum[b * 64 + h];
  const float pooled = s * (1.0f / (512.f * 64.f));
  out[2 + b] = pooled;

  float tot = pooled;
  float l0 = pooled * Wc[b * 2 + 0];
  float l1 = pooled * Wc[b * 2 + 1];
#pragma unroll
  for (int off = 32; off > 0; off >>= 1) {
    tot += __shfl_xor(tot, off);
    l0 += __shfl_xor(l0, off);
    l1 += __shfl_xor(l1, off);
  }
  if (b == 0) {
    out[0] = l0 + bc[0];
    out[1] = l1 + bc[1];
    out[66] = tot * (1.0f / 64.f);
  }
}

extern "C" void kernel_launch(void* const* d_in, const int* in_sizes, int n_in,
                              void* d_out, int out_size, void* d_ws, size_t ws_size,
                              hipStream_t stream) {
  const float* X    = (const float*)d_in[0];   // [64,512,64,16] -> [32768,1024]
  const float* W0   = (const float*)d_in[1];   // [1024,256]
  const float* b0   = (const float*)d_in[2];
  const float* W1   = (const float*)d_in[3];   // [256,128]
  const float* b1   = (const float*)d_in[4];
  const float* W2   = (const float*)d_in[5];   // [128,64]
  const float* b2   = (const float*)d_in[6];
  const float* ln1s = (const float*)d_in[7];
  const float* ln1b = (const float*)d_in[8];
  const float* ln2s = (const float*)d_in[9];
  const float* ln2b = (const float*)d_in[10];
  const float* Wc   = (const float*)d_in[11];  // [64,2]
  const float* bc   = (const float*)d_in[12];
  float* out = (float*)d_out;

  float* buf0 = (float*)d_ws;                          // 32768*256 = 8388608
  float* buf1 = buf0 + (size_t)32768 * 256;            // 32768*128 = 4194304
  float* buf2 = buf1 + (size_t)32768 * 128;            // 32768*64  = 2097152
  float* tsum = buf2 + (size_t)32768 * 64;             // 4096

  const int M = 32768;

  // Layer 0: [32768,1024]@[1024,256]
  gemm_bias<<<dim3(256 / 64, M / 64), 256, 0, stream>>>(X, W0, b0, buf0, M, 256, 1024);
  lif_scan<256, false><<<(BATCH * 256) / 256, 256, 0, stream>>>(buf0, nullptr);
  layernorm_inplace<256><<<M / 4, 256, 0, stream>>>(buf0, ln1s, ln1b);

  // Layer 1: [32768,256]@[256,128]
  gemm_bias<<<dim3(128 / 64, M / 64), 256, 0, stream>>>(buf0, W1, b1, buf1, M, 128, 256);
  lif_scan<128, false><<<(BATCH * 128) / 256, 256, 0, stream>>>(buf1, nullptr);
  layernorm_inplace<128><<<M / 4, 256, 0, stream>>>(buf1, ln2s, ln2b);

  // Layer 2: [32768,128]@[128,64]
  gemm_bias<<<dim3(64 / 64, M / 64), 256, 0, stream>>>(buf1, W2, b2, buf2, M, 64, 128);
  lif_scan<64, true><<<(BATCH * 64) / 256, 256, 0, stream>>>(buf2, tsum);

  finalize<<<1, 64, 0, stream>>>(tsum, Wc, bc, out);
}

// Round 2
// 220.823 us; speedup vs baseline: 1.6562x; 1.6562x over previous
//
#include <hip/hip_runtime.h>

#define T_STEPS 512
#define BATCH 64

// fp32 casts of np.exp(-1/20), np.exp(-1/5)
__device__ constexpr float ALPHA_ = 0.95122942450071400910f;
__device__ constexpr float BETA_  = 0.81873075307798185867f;

typedef __attribute__((ext_vector_type(8))) short bf16x8;
typedef __attribute__((ext_vector_type(4))) float f32x4;

__device__ inline unsigned short f2bf(float f) {
  union { float f; unsigned int u; } v{f};
  const unsigned int u = v.u;
  return (unsigned short)((u + 0x7FFFu + ((u >> 16) & 1u)) >> 16);
}

__device__ inline void gload16(const void* g, void* l) {
  __builtin_amdgcn_global_load_lds(
      (const __attribute__((address_space(1))) unsigned int*)g,
      (__attribute__((address_space(3))) unsigned int*)l, 16, 0, 0);
}

// truncate-pack 8 fp32 -> 8 bf16 (EXACT for spike values 0.0/1.0)
__device__ inline bf16x8 cvt8_trunc(f32x4 a, f32x4 b) {
  bf16x8 r;
  const unsigned int* ua = (const unsigned int*)&a;
  const unsigned int* ub = (const unsigned int*)&b;
  r[0] = (short)(ua[0] >> 16); r[1] = (short)(ua[1] >> 16);
  r[2] = (short)(ua[2] >> 16); r[3] = (short)(ua[3] >> 16);
  r[4] = (short)(ub[0] >> 16); r[5] = (short)(ub[1] >> 16);
  r[6] = (short)(ub[2] >> 16); r[7] = (short)(ub[3] >> 16);
  return r;
}

// ---------------------------------------------------------------------------
// Split-bf16 MFMA GEMM: C[M,N] = A_f32[M,K] @ (BThi+BTlo)[N,K]^T + bias
// A is fp32 in global (spikes, exact in bf16); staged raw via global_load_lds
// with XOR-swizzled SOURCE addresses, converted to bf16 at fragment read.
// BT hi/lo are bf16 [N,K], pre-swizzled by the split kernel.
// BM=BN=128, BK=32, 256 threads (4 waves, each 64x64 of 16x16x32 frags).
// ---------------------------------------------------------------------------
__global__ __launch_bounds__(256) void gemm_bf16_split(
    const float* __restrict__ A, const unsigned short* __restrict__ BThi,
    const unsigned short* __restrict__ BTlo, const float* __restrict__ bias,
    float* __restrict__ C, int M, int N, int K) {
  __shared__ char smem[32768];
  char* As = smem;           // 128 rows x 128 B (32 fp32)
  char* Bh = smem + 16384;   // 128 rows x 64 B (32 bf16)
  char* Bl = smem + 24576;   // 128 rows x 64 B

  const int tid = threadIdx.x;
  const int lane = tid & 63;
  const int wave = tid >> 6;
  const int wr = wave >> 1, wc = wave & 1;
  const int l15 = lane & 15, l4 = lane >> 4;
  const int row0 = blockIdx.y * 128, col0 = blockIdx.x * 128;

  const size_t Kb2 = (size_t)K * 2;   // bf16 row stride bytes
  const size_t Kb4 = (size_t)K * 4;   // fp32 row stride bytes
  const char* Abase = (const char*)A + (size_t)row0 * Kb4;
  const char* Bhbase = (const char*)BThi + (size_t)col0 * Kb2;
  const char* Blbase = (const char*)BTlo + (size_t)col0 * Kb2;

  f32x4 acc[4][4] = {};

  // precompute ds-read offsets
  int a_off0[4], b_off[4];
#pragma unroll
  for (int m = 0; m < 4; ++m) {
    const int r = wr * 64 + m * 16 + l15;
    a_off0[m] = r * 128 + ((l4 * 32) ^ ((r & 7) << 4));
  }
#pragma unroll
  for (int n = 0; n < 4; ++n) {
    const int r = wc * 64 + n * 16 + l15;
    b_off[n] = r * 64 + ((l4 * 16) ^ ((r & 3) << 4));
  }

  for (int k0 = 0; k0 < K; k0 += 32) {
    __syncthreads();
    // stage A: 16 KB, 4 issues; source swizzled so LDS is read-conflict-free
#pragma unroll
    for (int i = 0; i < 4; ++i) {
      const int j = i * 4096 + tid * 16;
      const int r = j >> 7, w = j & 127;
      gload16(Abase + (size_t)r * Kb4 + k0 * 4 + (w ^ ((r & 7) << 4)), As + j);
    }
    // stage B hi/lo: 8 KB each, 2 issues (swizzle pre-baked in the arrays)
#pragma unroll
    for (int i = 0; i < 2; ++i) {
      const int j = i * 4096 + tid * 16;
      const int r = j >> 6, w = j & 63;
      gload16(Bhbase + (size_t)r * Kb2 + k0 * 2 + w, Bh + j);
      gload16(Blbase + (size_t)r * Kb2 + k0 * 2 + w, Bl + j);
    }
    __syncthreads();

    bf16x8 af[4], bh[4], bl[4];
#pragma unroll
    for (int m = 0; m < 4; ++m) {
      const f32x4 lo = *(const f32x4*)(As + a_off0[m]);
      const f32x4 hi = *(const f32x4*)(As + (a_off0[m] ^ 16));
      // a_off0 has bit4 clear iff XOR mask flipped it; reconstruct order:
      // element k j=0..3 lives at (l4*32)^mask, j=4..7 at (l4*32+16)^mask.
      // (x ^ 16) with base (l4*32)^mask gives (l4*32+16)^mask. Order is (lo,hi)
      af[m] = cvt8_trunc(lo, hi);
    }
#pragma unroll
    for (int n = 0; n < 4; ++n) {
      bh[n] = *(const bf16x8*)(Bh + b_off[n]);
      bl[n] = *(const bf16x8*)(Bl + b_off[n]);
    }
#pragma unroll
    for (int m = 0; m < 4; ++m)
#pragma unroll
      for (int n = 0; n < 4; ++n) {
        acc[m][n] = __builtin_amdgcn_mfma_f32_16x16x32_bf16(af[m], bh[n], acc[m][n], 0, 0, 0);
        acc[m][n] = __builtin_amdgcn_mfma_f32_16x16x32_bf16(af[m], bl[n], acc[m][n], 0, 0, 0);
      }
  }

#pragma unroll
  for (int n = 0; n < 4; ++n) {
    const int c = col0 + wc * 64 + n * 16 + l15;
    const float bv = bias[c];
#pragma unroll
    for (int m = 0; m < 4; ++m) {
      const int rbase = row0 + wr * 64 + m * 16 + l4 * 4;
#pragma unroll
      for (int r = 0; r < 4; ++r)
        C[(size_t)(rbase + r) * N + c] = acc[m][n][r] + bv;
    }
  }
}

// ---------------------------------------------------------------------------
// W0 split + transpose + pre-swizzle: W[K,N] f32 -> hi/lo [N,K] bf16 with
// k-within-32 element index XORed by ((n&3)<<3) (matches GEMM's b_off swizzle).
// ---------------------------------------------------------------------------
__global__ void split_w(const float* __restrict__ W, unsigned short* __restrict__ hi,
                        unsigned short* __restrict__ lo, int K, int N) {
  const int idx = blockIdx.x * 256 + threadIdx.x;
  if (idx >= K * N) return;
  const int k = idx / N, n = idx % N;
  const float w = W[idx];
  const unsigned short h = f2bf(w);
  union { unsigned int u; float f; } hf{(unsigned int)h << 16};
  const unsigned short l = f2bf(w - hf.f);
  const int ks = (k & ~31) | ((k & 31) ^ ((n & 3) << 3));
  hi[(size_t)n * K + ks] = h;
  lo[(size_t)n * K + ks] = l;
}

// ---------------------------------------------------------------------------
// fp32 LDS-tiled GEMM (layers 1-2): C = A@B + bias. BM=BN=64, BK=16.
// ---------------------------------------------------------------------------
__global__ __launch_bounds__(256) void gemm_bias(
    const float* __restrict__ A, const float* __restrict__ B,
    const float* __restrict__ bias, float* __restrict__ C,
    int M, int N, int K) {
  __shared__ float Asm[16][64 + 4];
  __shared__ float Bsm[16][64 + 4];
  const int tid = threadIdx.x;
  const int tx = tid & 15;
  const int ty = tid >> 4;
  const int row0 = blockIdx.y * 64;
  const int col0 = blockIdx.x * 64;

  float acc[4][4] = {};

  const int a_m = tid >> 2;
  const int a_k = (tid & 3) * 4;
  const int b_k = tid >> 4;
  const int b_n = (tid & 15) * 4;

  const float* Aptr = A + (size_t)(row0 + a_m) * K + a_k;
  const float* Bptr = B + (size_t)b_k * N + col0 + b_n;

  for (int k0 = 0; k0 < K; k0 += 16) {
    const float4 av = *(const float4*)(Aptr + k0);
    const float4 bv = *(const float4*)(Bptr + (size_t)k0 * N);
    __syncthreads();
    Asm[a_k + 0][a_m] = av.x;
    Asm[a_k + 1][a_m] = av.y;
    Asm[a_k + 2][a_m] = av.z;
    Asm[a_k + 3][a_m] = av.w;
    *(float4*)&Bsm[b_k][b_n] = bv;
    __syncthreads();
#pragma unroll
    for (int k = 0; k < 16; ++k) {
      const float4 ra = *(const float4*)&Asm[k][ty * 4];
      const float4 rb = *(const float4*)&Bsm[k][tx * 4];
      acc[0][0] += ra.x * rb.x; acc[0][1] += ra.x * rb.y; acc[0][2] += ra.x * rb.z; acc[0][3] += ra.x * rb.w;
      acc[1][0] += ra.y * rb.x; acc[1][1] += ra.y * rb.y; acc[1][2] += ra.y * rb.z; acc[1][3] += ra.y * rb.w;
      acc[2][0] += ra.z * rb.x; acc[2][1] += ra.z * rb.y; acc[2][2] += ra.z * rb.z; acc[2][3] += ra.z * rb.w;
      acc[3][0] += ra.w * rb.x; acc[3][1] += ra.w * rb.y; acc[3][2] += ra.w * rb.z; acc[3][3] += ra.w * rb.w;
    }
  }

#pragma unroll
  for (int m = 0; m < 4; ++m) {
    const int r = row0 + ty * 4 + m;
#pragma unroll
    for (int n = 0; n < 4; ++n) {
      const int c = col0 + tx * 4 + n;
      C[(size_t)r * N + c] = acc[m][n] + bias[c];
    }
  }
}

// ---------------------------------------------------------------------------
// LIF scan over T (sequential), in-place. One thread per (b,h), 8x unrolled.
// ---------------------------------------------------------------------------
template <int H, bool ACCUM>
__global__ void lif_scan(float* __restrict__ xt, float* __restrict__ tsum) {
  const int n = blockIdx.x * blockDim.x + threadIdx.x;
  const int b = n / H;
  const int h = n % H;
  float* p = xt + (size_t)b * T_STEPS * H + h;

  float v = 0.f, cur = 0.f, ts = 0.f;
  for (int t = 0; t < T_STEPS; t += 8) {
    float x[8];
#pragma unroll
    for (int u = 0; u < 8; ++u) x[u] = p[u * H];
#pragma unroll
    for (int u = 0; u < 8; ++u) {
      cur = BETA_ * cur + x[u];
      v = ALPHA_ * v + cur;
      const float s = (v >= 1.f) ? 1.f : 0.f;
      p[u * H] = s;
      ts += s;
      v = (v >= 1.f) ? 0.f : v;
    }
    p += 8 * H;
  }
  if constexpr (ACCUM) tsum[n] = ts;
}

// ---------------------------------------------------------------------------
// LayerNorm in-place over last dim H. One wave per row.
// ---------------------------------------------------------------------------
template <int H>
__global__ __launch_bounds__(256) void layernorm_inplace(
    float* __restrict__ x, const float* __restrict__ scale,
    const float* __restrict__ bias) {
  const int wave = threadIdx.x >> 6;
  const int lane = threadIdx.x & 63;
  const int row = blockIdx.x * 4 + wave;
  float* p = x + (size_t)row * H;
  constexpr int PER = H / 64;

  float vals[PER];
#pragma unroll
  for (int j = 0; j < PER; ++j) vals[j] = p[lane + j * 64];

  float s = 0.f;
#pragma unroll
  for (int j = 0; j < PER; ++j) s += vals[j];
#pragma unroll
  for (int off = 32; off > 0; off >>= 1) s += __shfl_xor(s, off);
  const float m = s / (float)H;

  float vs = 0.f;
#pragma unroll
  for (int j = 0; j < PER; ++j) { const float d = vals[j] - m; vs += d * d; }
#pragma unroll
  for (int off = 32; off > 0; off >>= 1) vs += __shfl_xor(vs, off);
  const float var = vs / (float)H;
  const float inv = 1.0f / sqrtf(var + 1e-6f);

#pragma unroll
  for (int j = 0; j < PER; ++j) {
    const int c = lane + j * 64;
    p[c] = (vals[j] - m) * inv * scale[c] + bias[c];
  }
}

__global__ void finalize(const float* __restrict__ tsum,
                         const float* __restrict__ Wc,
                         const float* __restrict__ bc,
                         float* __restrict__ out) {
  const int b = threadIdx.x;  // 64 threads, one wave
  float s = 0.f;
  for (int h = 0; h < 64; ++h) s += tsum[b * 64 + h];
  const float pooled = s * (1.0f / (512.f * 64.f));
  out[2 + b] = pooled;

  float tot = pooled;
  float l0 = pooled * Wc[b * 2 + 0];
  float l1 = pooled * Wc[b * 2 + 1];
#pragma unroll
  for (int off = 32; off > 0; off >>= 1) {
    tot += __shfl_xor(tot, off);
    l0 += __shfl_xor(l0, off);
    l1 += __shfl_xor(l1, off);
  }
  if (b == 0) {
    out[0] = l0 + bc[0];
    out[1] = l1 + bc[1];
    out[66] = tot * (1.0f / 64.f);
  }
}

extern "C" void kernel_launch(void* const* d_in, const int* in_sizes, int n_in,
                              void* d_out, int out_size, void* d_ws, size_t ws_size,
                              hipStream_t stream) {
  const float* X    = (const float*)d_in[0];   // [64,512,64,16] -> [32768,1024]
  const float* W0   = (const float*)d_in[1];   // [1024,256]
  const float* b0   = (const float*)d_in[2];
  const float* W1   = (const float*)d_in[3];   // [256,128]
  const float* b1   = (const float*)d_in[4];
  const float* W2   = (const float*)d_in[5];   // [128,64]
  const float* b2   = (const float*)d_in[6];
  const float* ln1s = (const float*)d_in[7];
  const float* ln1b = (const float*)d_in[8];
  const float* ln2s = (const float*)d_in[9];
  const float* ln2b = (const float*)d_in[10];
  const float* Wc   = (const float*)d_in[11];  // [64,2]
  const float* bc   = (const float*)d_in[12];
  float* out = (float*)d_out;

  float* buf0 = (float*)d_ws;                          // 32768*256 f32
  float* buf1 = buf0 + (size_t)32768 * 256;            // 32768*128 f32
  float* buf2 = buf1 + (size_t)32768 * 128;            // 32768*64  f32
  float* tsum = buf2 + (size_t)32768 * 64;             // 4096 f32
  unsigned short* w0hi = (unsigned short*)(tsum + 4096);      // 256*1024 bf16
  unsigned short* w0lo = w0hi + (size_t)256 * 1024;

  const int M = 32768;

  // W0 split (hi/lo, transposed [N,K], pre-swizzled)
  split_w<<<(1024 * 256 + 255) / 256, 256, 0, stream>>>(W0, w0hi, w0lo, 1024, 256);

  // Layer 0: [32768,1024]@[1024,256] via split-bf16 MFMA
  gemm_bf16_split<<<dim3(256 / 128, M / 128), 256, 0, stream>>>(
      X, w0hi, w0lo, b0, buf0, M, 256, 1024);
  lif_scan<256, false><<<(BATCH * 256) / 256, 256, 0, stream>>>(buf0, nullptr);
  layernorm_inplace<256><<<M / 4, 256, 0, stream>>>(buf0, ln1s, ln1b);

  // Layer 1: [32768,256]@[256,128]
  gemm_bias<<<dim3(128 / 64, M / 64), 256, 0, stream>>>(buf0, W1, b1, buf1, M, 128, 256);
  lif_scan<128, false><<<(BATCH * 128) / 256, 256, 0, stream>>>(buf1, nullptr);
  layernorm_inplace<128><<<M / 4, 256, 0, stream>>>(buf1, ln2s, ln2b);

  // Layer 2: [32768,128]@[128,64]
  gemm_bias<<<dim3(64 / 64, M / 64), 256, 0, stream>>>(buf1, W2, b2, buf2, M, 64, 128);
  lif_scan<64, true><<<(BATCH * 64) / 256, 256, 0, stream>>>(buf2, tsum);

  finalize<<<1, 64, 0, stream>>>(tsum, Wc, bc, out);
}

// Round 3
// 154.980 us; speedup vs baseline: 2.3598x; 1.4249x over previous
//
#include <hip/hip_runtime.h>

#define T_STEPS 512
#define BATCH 64

// fp32 casts of np.exp(-1/20), np.exp(-1/5)
__device__ constexpr float ALPHA_ = 0.95122942450071400910f;
__device__ constexpr float BETA_  = 0.81873075307798185867f;

typedef __attribute__((ext_vector_type(8))) short bf16x8;
typedef __attribute__((ext_vector_type(4))) float f32x4;

__device__ inline unsigned short f2bf_rne(float f) {
  union { float f; unsigned int u; } v{f};
  const unsigned int u = v.u;
  return (unsigned short)((u + 0x7FFFu + ((u >> 16) & 1u)) >> 16);
}
__device__ inline float bf2f(unsigned short h) {
  union { unsigned int u; float f; } v{(unsigned int)h << 16};
  return v.f;
}

__device__ inline void gload16(const void* g, void* l) {
  __builtin_amdgcn_global_load_lds(
      (const __attribute__((address_space(1))) unsigned int*)g,
      (__attribute__((address_space(3))) unsigned int*)l, 16, 0, 0);
}

// truncate-pack 8 fp32 -> 8 bf16 (EXACT for spike values 0.0/1.0)
__device__ inline bf16x8 cvt8_trunc(f32x4 a, f32x4 b) {
  bf16x8 r;
  const unsigned int* ua = (const unsigned int*)&a;
  const unsigned int* ub = (const unsigned int*)&b;
  r[0] = (short)(ua[0] >> 16); r[1] = (short)(ua[1] >> 16);
  r[2] = (short)(ua[2] >> 16); r[3] = (short)(ua[3] >> 16);
  r[4] = (short)(ub[0] >> 16); r[5] = (short)(ub[1] >> 16);
  r[6] = (short)(ub[2] >> 16); r[7] = (short)(ub[3] >> 16);
  return r;
}

// ---------------------------------------------------------------------------
// Frag-linear MFMA GEMM. C[M,N] = op(A[M,K] @ W) with W = Bhi+Blo (split bf16),
// B arrays pre-laid-out in FRAGMENT-LINEAR order: for col-block cb, K-step kb,
// unit u in [0, BN*4): n = cb*BN + (u>>6)*16 + (u&15), k = kb*32 + ((u>>4)&3)*8 + jj.
// LDS reads are base + lane*16 (stride-1, conflict-free). A is either fp32
// (reg-staged + truncated to bf16 — exact for spikes) or bf16 (gload_lds,
// per-lane frag source, lane-linear dest).
// Epilogue: LNFOLD ? inv[r]*acc - mi[r]*u[c] + cvec[c] : acc + cvec[c].
// BM=128, 256 threads (4 waves: wr=wave>>1 over M, wc=wave&1 over N).
// ---------------------------------------------------------------------------
template <int BN, bool A_F32, bool LNFOLD>
__global__ __launch_bounds__(256) void gemm_mfma(
    const void* __restrict__ Av, const char* __restrict__ Bhi,
    const char* __restrict__ Blo, const float* __restrict__ uvec,
    const float* __restrict__ cvec, const float* __restrict__ invv,
    const float* __restrict__ miv, float* __restrict__ C,
    int M, int N, int K) {
  constexpr int NFPW = BN / 32;   // n-frags per wave
  constexpr int UB = BN * 4;      // B units per K-step
  __shared__ char As[8192];
  __shared__ char Bh[UB * 16];
  __shared__ char Bl[UB * 16];

  const int tid = threadIdx.x;
  const int lane = tid & 63;
  const int wave = tid >> 6;
  const int wr = wave >> 1, wc = wave & 1;
  const int l15 = lane & 15, l4 = lane >> 4;
  const int row0 = blockIdx.y * 128;
  const int col0 = blockIdx.x * BN;
  const int KB = K / 32;
  const int cbKB = blockIdx.x * KB;

  f32x4 acc[4][NFPW] = {};

  for (int kb = 0; kb < KB; ++kb) {
    const int k0 = kb * 32;
    f32x4 a0lo, a0hi, a1lo, a1hi;
    if constexpr (A_F32) {
      const float* A = (const float*)Av;
      const int r0 = tid >> 2, j0 = tid & 3;
      const float* p0 = A + (size_t)(row0 + r0) * K + k0 + j0 * 8;
      const float* p1 = A + (size_t)(row0 + 64 + r0) * K + k0 + j0 * 8;
      a0lo = *(const f32x4*)p0; a0hi = *(const f32x4*)(p0 + 4);
      a1lo = *(const f32x4*)p1; a1hi = *(const f32x4*)(p1 + 4);
    }
    __syncthreads();  // previous iteration's LDS reads complete
    if constexpr (A_F32) {
      const int r0 = tid >> 2, j0 = tid & 3;
      const int u0 = ((r0 >> 4) << 6) + (j0 << 4) + (r0 & 15);
      const int r1 = 64 + r0;
      const int u1 = ((r1 >> 4) << 6) + (j0 << 4) + (r1 & 15);
      *(bf16x8*)(As + u0 * 16) = cvt8_trunc(a0lo, a0hi);
      *(bf16x8*)(As + u1 * 16) = cvt8_trunc(a1lo, a1hi);
    } else {
      const char* A = (const char*)Av;  // bf16 [M][K]
#pragma unroll
      for (int i = 0; i < 2; ++i) {
        const int unit = (wave * 2 + i) * 64 + lane;
        const int r = ((unit >> 6) << 4) | (unit & 15);
        const int j = (unit >> 4) & 3;
        gload16(A + (size_t)(row0 + r) * (K * 2) + (size_t)(k0 + j * 8) * 2,
                As + unit * 16);
      }
    }
    {
      constexpr int nb = UB / 256;  // B gload insts per wave
#pragma unroll
      for (int i = 0; i < nb; ++i) {
        const int unit = (wave * nb + i) * 64 + lane;
        const size_t so = ((size_t)(cbKB + kb) * UB + unit) * 16;
        gload16(Bhi + so, Bh + unit * 16);
        gload16(Blo + so, Bl + unit * 16);
      }
    }
    __syncthreads();

    bf16x8 af[4], bhf[NFPW], blf[NFPW];
#pragma unroll
    for (int m = 0; m < 4; ++m)
      af[m] = *(const bf16x8*)(As + ((wr * 4 + m) * 64 + lane) * 16);
#pragma unroll
    for (int n = 0; n < NFPW; ++n) {
      const int u = ((wc * NFPW + n) * 64 + lane) * 16;
      bhf[n] = *(const bf16x8*)(Bh + u);
      blf[n] = *(const bf16x8*)(Bl + u);
    }
#pragma unroll
    for (int m = 0; m < 4; ++m)
#pragma unroll
      for (int n = 0; n < NFPW; ++n) {
        acc[m][n] = __builtin_amdgcn_mfma_f32_16x16x32_bf16(af[m], bhf[n], acc[m][n], 0, 0, 0);
        acc[m][n] = __builtin_amdgcn_mfma_f32_16x16x32_bf16(af[m], blf[n], acc[m][n], 0, 0, 0);
      }
  }

#pragma unroll
  for (int m = 0; m < 4; ++m) {
    const int rbase = row0 + (wr * 4 + m) * 16 + l4 * 4;
    f32x4 iv, mv;
    if constexpr (LNFOLD) {
      iv = *(const f32x4*)(invv + rbase);
      mv = *(const f32x4*)(miv + rbase);
    }
#pragma unroll
    for (int n = 0; n < NFPW; ++n) {
      const int c = col0 + (wc * NFPW + n) * 16 + l15;
      float uu = 0.f;
      const float cc = cvec[c];
      if constexpr (LNFOLD) uu = uvec[c];
#pragma unroll
      for (int r = 0; r < 4; ++r) {
        float v;
        if constexpr (LNFOLD) v = iv[r] * acc[m][n][r] - mv[r] * uu + cc;
        else v = acc[m][n][r] + cc;
        C[(size_t)(rbase + r) * N + c] = v;
      }
    }
  }
}

// ---------------------------------------------------------------------------
// Prep: W[K,N] f32 (optionally scaled by s[k]) -> split hi/lo bf16 in the
// fragment-linear global layout consumed by gemm_mfma.
// ---------------------------------------------------------------------------
template <int BN>
__global__ void prep_split(const float* __restrict__ W, const float* __restrict__ s,
                           char* __restrict__ hi, char* __restrict__ lo,
                           int K, int N) {
  const int g = blockIdx.x * 256 + threadIdx.x;
  const int total = (K * N) / 8;
  if (g >= total) return;
  constexpr int UB = BN * 4;
  const int KB = K / 32;
  const int unit = g % UB;
  const int kb = (g / UB) % KB;
  const int cb = g / (UB * KB);
  const int n = cb * BN + ((unit >> 6) << 4) + (unit & 15);
  const int kbase = kb * 32 + ((unit >> 4) & 3) * 8;
  short h8[8], l8[8];
#pragma unroll
  for (int jj = 0; jj < 8; ++jj) {
    const int k = kbase + jj;
    float w = W[(size_t)k * N + n];
    if (s) w *= s[k];
    const unsigned short hb = f2bf_rne(w);
    const unsigned short lb = f2bf_rne(w - bf2f(hb));
    h8[jj] = (short)hb; l8[jj] = (short)lb;
  }
  *(bf16x8*)(hi + (size_t)g * 16) = *(const bf16x8*)h8;
  *(bf16x8*)(lo + (size_t)g * 16) = *(const bf16x8*)l8;
}

// u[n] = sum_k s[k]*W[k,n];  c[n] = sum_k b[k]*W[k,n] + bias2[n]. Block per n.
__global__ __launch_bounds__(256) void prep_consts(
    const float* __restrict__ W, const float* __restrict__ s,
    const float* __restrict__ b, const float* __restrict__ bias2,
    float* __restrict__ u, float* __restrict__ c, int K, int N) {
  const int n = blockIdx.x;
  const int t = threadIdx.x;
  float us = 0.f, cs = 0.f;
  for (int k = t; k < K; k += 256) {
    const float w = W[(size_t)k * N + n];
    us += s[k] * w;
    cs += b[k] * w;
  }
  __shared__ float su[256], sc[256];
  su[t] = us; sc[t] = cs;
  __syncthreads();
  for (int o = 128; o > 0; o >>= 1) {
    if (t < o) { su[t] += su[t + o]; sc[t] += sc[t + o]; }
    __syncthreads();
  }
  if (t == 0) { u[n] = su[0]; c[n] = sc[0] + bias2[n]; }
}

// ---------------------------------------------------------------------------
// Row stats of a spike matrix (values in {0,1}): mean m = rowsum/K,
// var = m*(1-m)  (since x^2 = x), inv = 1/sqrt(var+eps). One wave per row.
// ---------------------------------------------------------------------------
template <int K>
__global__ __launch_bounds__(256) void rowstats(
    const unsigned short* __restrict__ sp, float* __restrict__ invv,
    float* __restrict__ miv) {
  const int wave = threadIdx.x >> 6, lane = threadIdx.x & 63;
  const int row = blockIdx.x * 4 + wave;
  const unsigned short* p = sp + (size_t)row * K;
  float ssum = 0.f;
  if constexpr (K == 256) {
    const ushort4 v = *(const ushort4*)(p + lane * 4);
    ssum = bf2f(v.x) + bf2f(v.y) + bf2f(v.z) + bf2f(v.w);
  } else {  // K == 128
    const ushort2 v = *(const ushort2*)(p + lane * 2);
    ssum = bf2f(v.x) + bf2f(v.y);
  }
#pragma unroll
  for (int o = 32; o > 0; o >>= 1) ssum += __shfl_xor(ssum, o);
  if (lane == 0) {
    const float m = ssum / (float)K;
    const float inv = 1.0f / sqrtf(m * (1.f - m) + 1e-6f);
    invv[row] = inv;
    miv[row] = m * inv;
  }
}

// ---------------------------------------------------------------------------
// LIF scan over T, one thread per (b,h); reads fp32 currents, writes bf16
// spikes (exact) and/or per-(b,h) spike counts. 16x unrolled loads.
// ---------------------------------------------------------------------------
template <int H, bool SPIKE_OUT, bool ACCUM>
__global__ void lif_scan(const float* __restrict__ xt,
                         unsigned short* __restrict__ sp,
                         float* __restrict__ tsum) {
  const int n = blockIdx.x * 64 + threadIdx.x;
  const int b = n / H, h = n % H;
  const float* p = xt + (size_t)b * T_STEPS * H + h;
  unsigned short* q = nullptr;
  if constexpr (SPIKE_OUT) q = sp + (size_t)b * T_STEPS * H + h;

  float v = 0.f, cur = 0.f, ts = 0.f;
  for (int t = 0; t < T_STEPS; t += 16) {
    float x[16];
#pragma unroll
    for (int u = 0; u < 16; ++u) x[u] = p[(size_t)u * H];
#pragma unroll
    for (int u = 0; u < 16; ++u) {
      cur = BETA_ * cur + x[u];
      v = ALPHA_ * v + cur;
      const bool sb = (v >= 1.f);
      if constexpr (SPIKE_OUT) q[(size_t)u * H] = sb ? 0x3F80 : 0;
      if constexpr (ACCUM) ts += sb ? 1.f : 0.f;
      v = sb ? 0.f : v;
    }
    p += (size_t)16 * H;
    if constexpr (SPIKE_OUT) q += (size_t)16 * H;
  }
  if constexpr (ACCUM) tsum[n] = ts;
}

__global__ void finalize(const float* __restrict__ tsum,
                         const float* __restrict__ Wc,
                         const float* __restrict__ bc,
                         float* __restrict__ out) {
  const int b = threadIdx.x;  // 64 threads, one wave
  float s = 0.f;
#pragma unroll 8
  for (int h = 0; h < 64; ++h) s += tsum[b * 64 + h];
  const float pooled = s * (1.0f / (512.f * 64.f));
  out[2 + b] = pooled;

  float tot = pooled;
  float l0 = pooled * Wc[b * 2 + 0];
  float l1 = pooled * Wc[b * 2 + 1];
#pragma unroll
  for (int off = 32; off > 0; off >>= 1) {
    tot += __shfl_xor(tot, off);
    l0 += __shfl_xor(l0, off);
    l1 += __shfl_xor(l1, off);
  }
  if (b == 0) {
    out[0] = l0 + bc[0];
    out[1] = l1 + bc[1];
    out[66] = tot * (1.0f / 64.f);
  }
}

extern "C" void kernel_launch(void* const* d_in, const int* in_sizes, int n_in,
                              void* d_out, int out_size, void* d_ws, size_t ws_size,
                              hipStream_t stream) {
  const float* X    = (const float*)d_in[0];   // [64,512,64,16] -> [32768,1024]
  const float* W0   = (const float*)d_in[1];   // [1024,256]
  const float* b0   = (const float*)d_in[2];
  const float* W1   = (const float*)d_in[3];   // [256,128]
  const float* b1   = (const float*)d_in[4];
  const float* W2   = (const float*)d_in[5];   // [128,64]
  const float* b2   = (const float*)d_in[6];
  const float* ln1s = (const float*)d_in[7];
  const float* ln1b = (const float*)d_in[8];
  const float* ln2s = (const float*)d_in[9];
  const float* ln2b = (const float*)d_in[10];
  const float* Wc   = (const float*)d_in[11];  // [64,2]
  const float* bc   = (const float*)d_in[12];
  float* out = (float*)d_out;

  char* w = (char*)d_ws;
  float* buf0 = (float*)w;                       // [32768,256] f32 = 33554432 B
  float* buf1 = (float*)w;                       // alias: buf0 dead after scan0
  float* buf2 = (float*)(w + 16777216);          // [32768,64] f32, after buf1
  size_t off = 33554432;
  unsigned short* sp0 = (unsigned short*)(w + off); off += 16777216;  // [32768,256] bf16
  unsigned short* sp1 = (unsigned short*)(w + off); off += 8388608;   // [32768,128] bf16
  char* hi0 = w + off; off += 524288;
  char* lo0 = w + off; off += 524288;
  char* hi1 = w + off; off += 65536;
  char* lo1 = w + off; off += 65536;
  char* hi2 = w + off; off += 16384;
  char* lo2 = w + off; off += 16384;
  float* u1 = (float*)(w + off); off += 512;
  float* c1 = (float*)(w + off); off += 512;
  float* u2 = (float*)(w + off); off += 256;
  float* c2 = (float*)(w + off); off += 256;
  float* inv1 = (float*)(w + off); off += 131072;
  float* mi1  = (float*)(w + off); off += 131072;
  float* inv2 = (float*)(w + off); off += 131072;
  float* mi2  = (float*)(w + off); off += 131072;
  float* tsum = (float*)(w + off); off += 16384;

  const int M = 32768;

  // --- weight prep (frag-linear split hi/lo + LN-fold constants) ---
  prep_split<128><<<128, 256, 0, stream>>>(W0, nullptr, hi0, lo0, 1024, 256);
  prep_split<128><<<16, 256, 0, stream>>>(W1, ln1s, hi1, lo1, 256, 128);
  prep_split<64><<<4, 256, 0, stream>>>(W2, ln2s, hi2, lo2, 128, 64);
  prep_consts<<<128, 256, 0, stream>>>(W1, ln1s, ln1b, b1, u1, c1, 256, 128);
  prep_consts<<<64, 256, 0, stream>>>(W2, ln2s, ln2b, b2, u2, c2, 128, 64);

  // --- layer 0: xt = X @ W0 + b0 ; scan -> bf16 spikes ---
  gemm_mfma<128, true, false><<<dim3(2, M / 128), 256, 0, stream>>>(
      X, hi0, lo0, nullptr, b0, nullptr, nullptr, buf0, M, 256, 1024);
  lif_scan<256, true, false><<<(BATCH * 256) / 64, 64, 0, stream>>>(buf0, sp0, nullptr);

  // --- layer 1: LN folded into GEMM (spike rows: var = m(1-m)) ---
  rowstats<256><<<M / 4, 256, 0, stream>>>(sp0, inv1, mi1);
  gemm_mfma<128, false, true><<<dim3(1, M / 128), 256, 0, stream>>>(
      sp0, hi1, lo1, u1, c1, inv1, mi1, buf1, M, 128, 256);
  lif_scan<128, true, false><<<(BATCH * 128) / 64, 64, 0, stream>>>(buf1, sp1, nullptr);

  // --- layer 2 ---
  rowstats<128><<<M / 4, 256, 0, stream>>>(sp1, inv2, mi2);
  gemm_mfma<64, false, true><<<dim3(1, M / 128), 256, 0, stream>>>(
      sp1, hi2, lo2, u2, c2, inv2, mi2, buf2, M, 64, 128);
  lif_scan<64, false, true><<<(BATCH * 64) / 64, 64, 0, stream>>>(buf2, nullptr, tsum);

  finalize<<<1, 64, 0, stream>>>(tsum, Wc, bc, out);
}